// Round 5
// baseline (3126.209 us; speedup 1.0000x reference)
//
#include <hip/hip_runtime.h>
#include <hip/hip_bf16.h>

#define B_ 2048
#define T_ 128
#define F_ 64
#define U_ 512
#define FOURU 2048
#define OUTS 32
#define KTOT 576      // 64 (x) + 512 (h)

typedef __attribute__((ext_vector_type(8))) short bf16x8;
typedef __attribute__((ext_vector_type(4))) float f32x4;

// workspace layout (bytes). First 20480 B zeroed every launch:
//   dw [0..4095]      flags: group gb, producer gu at dw gb*256+gu*16 (64B spaced)
//   dw [4096..4351]   regist counters (16 groups x 16dw)
//   dw [4352..4607]   xcd table (16 groups x 16dw)
#define OFF_CNT   0
#define OFF_HBUF  20480
#define OFF_WT    (OFF_HBUF + 2*B_*U_*2)
#define OFF_WDEC  (OFF_WT + FOURU*KTOT*2)
#define OFF_DWT   (OFF_WDEC + FOURU*U_*2)
#define OFF_BDEC  (OFF_DWT + F_*U_*2)
#define OFF_XBF   (OFF_BDEC + FOURU*4)
#define WS_TOTAL  (OFF_XBF + (size_t)T_*B_*F_*2)

__device__ __forceinline__ short f2bf(float f) {
  union { float f; unsigned u; } a; a.f = f;
  unsigned u = a.u;
  unsigned r = u + 0x7FFFu + ((u >> 16) & 1u);  // RNE
  return (short)(r >> 16);
}
__device__ __forceinline__ float sigm(float x){ return 1.0f/(1.0f+__expf(-x)); }
__device__ __forceinline__ float tanh_(float x){ return 1.0f - 2.0f/(1.0f+__expf(2.0f*x)); }

template<int CTRL>
__device__ __forceinline__ float dppb(float x) {
  union { float f; int i; } a, b; a.f = x;
  b.i = __builtin_amdgcn_mov_dpp(a.i, CTRL, 0xF, 0xF, true);
  return b.f;
}
__device__ __forceinline__ float sel4(float x0, float x1, float x2, float x3, int qq) {
  float lo = (qq & 1) ? x1 : x0;
  float hi = (qq & 1) ? x3 : x2;
  return (qq & 2) ? hi : lo;
}

// ---------------- prep kernels ----------------
__global__ void prep_wt(const float* __restrict__ Wx, const float* __restrict__ Wh,
                        short* __restrict__ Wt) {
  int idx = blockIdx.x*256 + threadIdx.x;
  if (idx >= FOURU*KTOT) return;
  int c = idx / KTOT, k = idx % KTOT;
  float v = (k < F_) ? Wx[(size_t)k*FOURU + c] : Wh[(size_t)(k-F_)*FOURU + c];
  Wt[idx] = f2bf(v);
}
__global__ void prep_wdec(const float* __restrict__ Wh, const float* __restrict__ Wx,
                          const float* __restrict__ Dw, short* __restrict__ Wdec) {
  int idx = blockIdx.x*256 + threadIdx.x;
  if (idx >= FOURU*U_) return;
  int c = idx / U_, u = idx % U_;
  float a = Wh[(size_t)u*FOURU + c];
  for (int f=0; f<F_; ++f) a += Dw[u*F_ + f] * Wx[(size_t)f*FOURU + c];
  Wdec[idx] = f2bf(a);
}
__global__ void prep_bdec(const float* __restrict__ bv, const float* __restrict__ db,
                          const float* __restrict__ Wx, float* __restrict__ bdec) {
  int c = blockIdx.x*256 + threadIdx.x;
  if (c >= FOURU) return;
  float a = bv[c];
  for (int f=0; f<F_; ++f) a += db[f]*Wx[(size_t)f*FOURU + c];
  bdec[c] = a;
}
__global__ void prep_dwt(const float* __restrict__ Dw, short* __restrict__ Dwt) {
  int idx = blockIdx.x*256 + threadIdx.x;
  if (idx >= F_*U_) return;
  int f = idx / U_, u = idx % U_;
  Dwt[idx] = f2bf(Dw[u*F_ + f]);
}
__global__ void prep_x(const float* __restrict__ in, short* __restrict__ xbf) {
  int idx = blockIdx.x*256 + threadIdx.x;
  if (idx >= T_*B_*F_) return;
  int f = idx % F_, b = (idx / F_) % B_, t = idx / (F_*B_);
  xbf[idx] = f2bf(in[((size_t)b*T_ + t)*F_ + f]);
}

// ---------------- main persistent kernel ----------------
// 1024 threads = 16 waves, 1 block/CU -> 4 waves/SIMD.
// LDS weights: 128 cols (col = unit*4 + gate, unit-major) x 576 K, XOR-swizzled
// 16B granules: granule g stored at (g ^ (col&7)) -> all ds_read_b128 2-way (free).
__global__ __launch_bounds__(1024, 4) void lstm_main(
    const short* __restrict__ xbf, const short* __restrict__ Wt,
    const short* __restrict__ Wdec, const short* __restrict__ Dwt,
    const float* __restrict__ bvec, const float* __restrict__ bdec,
    const float* __restrict__ dbv, short* hbuf, unsigned* cnt,
    float* __restrict__ out)
{
  __shared__ short wlds[128*KTOT];   // 147,456 B
  __shared__ int sSame;
  const int tid = threadIdx.x;
  const int bidx = blockIdx.x;
  const int gb = (bidx & 7)*2 + (bidx >> 7);   // batch group 0..15
  const int gu = (bidx >> 3) & 15;             // unit group 0..15

  unsigned* flags  = cnt + gb*256;             // 16 producer flags, 64B spaced
  unsigned* myFlag = flags + gu*16;
  unsigned* regCnt = cnt + 4096 + gb*16;
  unsigned* xcdTab = cnt + 4352 + gb*16;

  // ---- runtime XCD-uniformity check for this group ----
  {
    unsigned xcc;
    asm volatile("s_getreg_b32 %0, hwreg(HW_REG_XCC_ID)" : "=s"(xcc));
    if (tid == 0) {
      __hip_atomic_store(&xcdTab[gu], xcc + 1u, __ATOMIC_RELAXED, __HIP_MEMORY_SCOPE_AGENT);
      __hip_atomic_fetch_add(regCnt, 1u, __ATOMIC_RELEASE, __HIP_MEMORY_SCOPE_AGENT);
      while (__hip_atomic_fetch_add(regCnt, 0u, __ATOMIC_RELAXED, __HIP_MEMORY_SCOPE_AGENT) < 16u)
        __builtin_amdgcn_s_sleep(1);
      __builtin_amdgcn_fence(__ATOMIC_ACQUIRE, "agent");
      unsigned x0 = __hip_atomic_load(&xcdTab[0], __ATOMIC_RELAXED, __HIP_MEMORY_SCOPE_AGENT);
      int same = 1;
      for (int i = 1; i < 16; ++i)
        same &= (__hip_atomic_load(&xcdTab[i], __ATOMIC_RELAXED, __HIP_MEMORY_SCOPE_AGENT) == x0);
      sSame = same;
    }
  }

  // ---- fill LDS weights (warm: full K=576), unit-major + swizzle ----
  {
    const int c = tid >> 3, q8 = tid & 7;
    const int gcol = (c & 3)*512 + gu*32 + (c >> 2);   // gate-major global col
    const int cx = c & 7;
    #pragma unroll
    for (int j = 0; j < 9; ++j) {
      const int g = q8*9 + j;                          // granule 0..71
      *(bf16x8*)(wlds + (size_t)c*KTOT + (size_t)(g ^ cx)*8) =
        *(const bf16x8*)(Wt + (size_t)gcol*KTOT + (size_t)g*8);
    }
  }
  __syncthreads();
  const bool fastSync = (sSame != 0);

  const int w  = tid >> 6, lane = tid & 63;
  const int wm = w >> 2, cq = w & 3;          // 4 row-groups x 4 col-quarters
  const int l15 = lane & 15, kh = lane >> 4;
  const int v = l15 >> 2, q = l15 & 3;        // unit-in-4 / gate
  const int R0 = gb*128, U0 = gu*32;
  const int cswz = l15 & 7;

  // bias (own gate q, units f*4+v of this quarter)
  float bia[2], biaD[2];
  #pragma unroll
  for (int f = 0; f < 2; ++f) {
    const int uc = U0 + cq*8 + f*4 + v;
    bia[f]  = bvec[q*512 + uc];
    biaD[f] = bdec[q*512 + uc];
  }

  float cst[2][2] = {{0.f,0.f},{0.f,0.f}};    // c-state, row kh*4+q only
  const int rowA = R0 + wm*32 + l15;

  f32x4 acc[2][2];
  #pragma unroll
  for (int a = 0; a < 2; ++a)
    #pragma unroll
    for (int f = 0; f < 2; ++f) acc[a][f] = (f32x4){0.f,0.f,0.f,0.f};

  // x-part helper (K 0..63, granules 0..7)
  auto do_x = [&](int tt) {
    const short* xp = xbf + ((size_t)tt*B_ + rowA)*F_ + kh*8;
    bf16x8 X0a = *(const bf16x8*)(xp);
    bf16x8 X1a = *(const bf16x8*)(xp + 16*F_);
    bf16x8 X0b = *(const bf16x8*)(xp + 32);
    bf16x8 X1b = *(const bf16x8*)(xp + 16*F_ + 32);
    #pragma unroll
    for (int kx = 0; kx < 2; ++kx) {
      const int gsw = (kx*4 + kh) ^ cswz;
      bf16x8 B0 = *(const bf16x8*)(wlds + (size_t)(cq*32 + l15)*KTOT + (size_t)gsw*8);
      bf16x8 B1 = *(const bf16x8*)(wlds + (size_t)(cq*32 + 16 + l15)*KTOT + (size_t)gsw*8);
      bf16x8 Xa = kx ? X0b : X0a;
      bf16x8 Xb = kx ? X1b : X1a;
      acc[0][0] = __builtin_amdgcn_mfma_f32_16x16x32_bf16(Xa, B0, acc[0][0], 0,0,0);
      acc[0][1] = __builtin_amdgcn_mfma_f32_16x16x32_bf16(Xa, B1, acc[0][1], 0,0,0);
      acc[1][0] = __builtin_amdgcn_mfma_f32_16x16x32_bf16(Xb, B0, acc[1][0], 0,0,0);
      acc[1][1] = __builtin_amdgcn_mfma_f32_16x16x32_bf16(Xb, B1, acc[1][1], 0,0,0);
    }
  };
  do_x(0);   // h(0)=0, so step 0 is x-part + zero h-chunks

  for (int t = 0; t < 160; ++t) {
    if (t == 128) {   // swap k-region 64..575 (granules 8..71) to folded Wdec
      const int c = tid >> 3, q8 = tid & 7;
      const int gcol = (c & 3)*512 + gu*32 + (c >> 2);
      const int cx = c & 7;
      #pragma unroll
      for (int j = 0; j < 8; ++j) {
        const int g = 8 + q8*8 + j;
        *(bf16x8*)(wlds + (size_t)c*KTOT + (size_t)(g ^ cx)*8) =
          *(const bf16x8*)(Wdec + (size_t)gcol*U_ + (size_t)(g-8)*8);
      }
      __syncthreads();
    }

    const short* hcur = hbuf + (size_t)(t & 1)*B_*U_;
    short* hnxt = hbuf + (size_t)((t+1) & 1)*B_*U_;

    // L1 invalidate once per step: all h reads below are post-flag -> fresh L2,
    // and normal (cached) loads let L1 dedupe the 4x cross-wave A-read overlap.
    asm volatile("buffer_inv sc0" ::: "memory");
    asm volatile("s_waitcnt vmcnt(0)" ::: "memory");

    // ---- pipelined per-producer chunk loop ----
    unsigned fvq[2] = {0u, 0u};
    if (fastSync) {
      fvq[1] = __hip_atomic_load(&flags[((gu+1)&15)*16], __ATOMIC_RELAXED, __HIP_MEMORY_SCOPE_AGENT);
      fvq[0] = __hip_atomic_load(&flags[((gu+2)&15)*16], __ATOMIC_RELAXED, __HIP_MEMORY_SCOPE_AGENT);
    }
    #pragma unroll
    for (int i = 0; i < 16; ++i) {
      const int ks = (gu + i) & 15;          // self-chunk first, staggered order
      if (i > 0) {
        if (fastSync) {
          unsigned vv = fvq[i & 1];
          if (vv < (unsigned)t) {
            const unsigned* fp = &flags[ks*16];
            do {
              __builtin_amdgcn_s_sleep(1);
              vv = __hip_atomic_load(fp, __ATOMIC_RELAXED, __HIP_MEMORY_SCOPE_AGENT);
            } while (vv < (unsigned)t);
          }
        } else {
          unsigned* fp = &flags[ks*16];
          while (__hip_atomic_fetch_add(fp, 0u, __ATOMIC_RELAXED, __HIP_MEMORY_SCOPE_AGENT) < (unsigned)t)
            __builtin_amdgcn_s_sleep(1);
          __builtin_amdgcn_fence(__ATOMIC_ACQUIRE, "agent");
        }
        asm volatile("" ::: "memory");       // pin A-loads after the flag check
      }
      const short* hp = hcur + (size_t)rowA*U_ + ks*32 + kh*8;
      bf16x8 A0 = *(const bf16x8*)(hp);
      bf16x8 A1 = *(const bf16x8*)(hp + 16*U_);
      if (fastSync && i >= 1 && i < 14)      // distance-2 flag prefetch
        fvq[i & 1] = __hip_atomic_load(&flags[((gu+i+2)&15)*16], __ATOMIC_RELAXED, __HIP_MEMORY_SCOPE_AGENT);
      const int gsw = (8 + ks*4 + kh) ^ cswz;
      bf16x8 B0 = *(const bf16x8*)(wlds + (size_t)(cq*32 + l15)*KTOT + (size_t)gsw*8);
      bf16x8 B1 = *(const bf16x8*)(wlds + (size_t)(cq*32 + 16 + l15)*KTOT + (size_t)gsw*8);
      acc[0][0] = __builtin_amdgcn_mfma_f32_16x16x32_bf16(A0, B0, acc[0][0], 0,0,0);
      acc[0][1] = __builtin_amdgcn_mfma_f32_16x16x32_bf16(A0, B1, acc[0][1], 0,0,0);
      acc[1][0] = __builtin_amdgcn_mfma_f32_16x16x32_bf16(A1, B0, acc[1][0], 0,0,0);
      acc[1][1] = __builtin_amdgcn_mfma_f32_16x16x32_bf16(A1, B1, acc[1][1], 0,0,0);
    }

    // ---- elementwise: quad-DPP gate gather, each lane owns row kh*4+q ----
    {
      const bool warm = (t < T_);
      #pragma unroll
      for (int a = 0; a < 2; ++a)
      #pragma unroll
      for (int f = 0; f < 2; ++f) {
        const float bb = warm ? bia[f] : biaD[f];
        float z0 = acc[a][f][0] + bb, z1 = acc[a][f][1] + bb;
        float z2 = acc[a][f][2] + bb, z3 = acc[a][f][3] + bb;
        float zi = sel4(dppb<0x00>(z0), dppb<0x00>(z1), dppb<0x00>(z2), dppb<0x00>(z3), q);
        float zf = sel4(dppb<0x55>(z0), dppb<0x55>(z1), dppb<0x55>(z2), dppb<0x55>(z3), q);
        float zg = sel4(dppb<0xAA>(z0), dppb<0xAA>(z1), dppb<0xAA>(z2), dppb<0xAA>(z3), q);
        float zo = sel4(dppb<0xFF>(z0), dppb<0xFF>(z1), dppb<0xFF>(z2), dppb<0xFF>(z3), q);
        float ig = sigm(zi), fg = sigm(zf), gg = tanh_(zg), og = sigm(zo);
        float c2 = fmaf(fg, cst[a][f], ig*gg);
        cst[a][f] = c2;
        float h2 = og*tanh_(c2);
        hnxt[(size_t)(R0 + wm*32 + a*16 + kh*4 + q)*U_ + U0 + cq*8 + f*4 + v] = f2bf(h2);
      }
    }

    // ---- pred s = t-128 (pre-flag: hcur stable; distributed gu<8, w<4) ----
    if (t >= 128 && gu < 8 && w < 4) {
      const int s = t - 128;
      const int pr0 = R0 + gu*16 + l15;
      f32x4 pa = {0.f,0.f,0.f,0.f};
      #pragma unroll
      for (int ks2 = 0; ks2 < 16; ++ks2) {
        bf16x8 a2 = *(const bf16x8*)(hcur + (size_t)pr0*U_ + ks2*32 + kh*8);
        bf16x8 b2 = *(const bf16x8*)(Dwt + (size_t)(w*16 + l15)*U_ + ks2*32 + kh*8);
        pa = __builtin_amdgcn_mfma_f32_16x16x32_bf16(a2, b2, pa, 0,0,0);
      }
      const int col = w*16 + l15;
      const float dbc = dbv[col];
      #pragma unroll
      for (int r = 0; r < 4; ++r) {
        const int orow = R0 + gu*16 + kh*4 + r;
        out[((size_t)orow*OUTS + s)*F_ + col] = pa[r] + dbc;
      }
    }

    // ---- release: all waves drained (syncthreads emits vmcnt(0)), set flag ----
    __syncthreads();
    if (tid == 0) {
      if (fastSync)
        __hip_atomic_store(myFlag, (unsigned)(t+1), __ATOMIC_RELAXED, __HIP_MEMORY_SCOPE_AGENT);
      else
        __hip_atomic_fetch_add(myFlag, 1u, __ATOMIC_RELEASE, __HIP_MEMORY_SCOPE_AGENT);
    }

    // ---- next step's x-part (shadows inter-block latency) or zero acc ----
    #pragma unroll
    for (int a = 0; a < 2; ++a)
      #pragma unroll
      for (int f = 0; f < 2; ++f) acc[a][f] = (f32x4){0.f,0.f,0.f,0.f};
    if (t + 1 < T_) do_x(t+1);
  }
}

extern "C" void kernel_launch(void* const* d_in, const int* in_sizes, int n_in,
                              void* d_out, int out_size, void* d_ws, size_t ws_size,
                              hipStream_t stream) {
  const float* inputs = (const float*)d_in[0];
  const float* Wx = (const float*)d_in[1];
  const float* Wh = (const float*)d_in[2];
  const float* bv = (const float*)d_in[3];
  const float* Dw = (const float*)d_in[4];
  const float* db = (const float*)d_in[5];
  float* out = (float*)d_out;
  char* ws = (char*)d_ws;
  if (ws_size < WS_TOTAL) return;   // fail loudly (output stays poisoned)

  unsigned* cnt = (unsigned*)(ws + OFF_CNT);
  short* hbuf = (short*)(ws + OFF_HBUF);
  short* Wt   = (short*)(ws + OFF_WT);
  short* Wdec = (short*)(ws + OFF_WDEC);
  short* Dwt  = (short*)(ws + OFF_DWT);
  float* bdec = (float*)(ws + OFF_BDEC);
  short* xbf  = (short*)(ws + OFF_XBF);

  // zero sync area + h0 buffer (every launch -> deterministic)
  hipMemsetAsync(d_ws, 0, OFF_HBUF + (size_t)B_*U_*2, stream);
  prep_wt  <<<(FOURU*KTOT+255)/256, 256, 0, stream>>>(Wx, Wh, Wt);
  prep_wdec<<<(FOURU*U_ +255)/256, 256, 0, stream>>>(Wh, Wx, Dw, Wdec);
  prep_bdec<<<(FOURU     +255)/256, 256, 0, stream>>>(bv, db, Wx, bdec);
  prep_dwt <<<(F_*U_     +255)/256, 256, 0, stream>>>(Dw, Dwt);
  prep_x   <<<(T_*B_*F_  +255)/256, 256, 0, stream>>>(inputs, xbf);
  lstm_main<<<256, 1024, 0, stream>>>(xbf, Wt, Wdec, Dwt, bv, bdec, db, hbuf, cnt, out);
}

// Round 6
// 3095.936 us; speedup vs baseline: 1.0098x; 1.0098x over previous
//
#include <hip/hip_runtime.h>
#include <hip/hip_bf16.h>

#define B_ 2048
#define T_ 128
#define F_ 64
#define U_ 512
#define FOURU 2048
#define OUTS 32
#define KTOT 576      // 64 (x) + 512 (h)

typedef __attribute__((ext_vector_type(8))) short bf16x8;
typedef __attribute__((ext_vector_type(4))) float f32x4;

// workspace layout (bytes). First 20480 B zeroed every launch:
//   dw [0..4095]      flags: group gb, producer gu at dw gb*256+gu*16 (64B spaced)
//   dw [4096..4351]   regist counters (16 groups x 16dw)
//   dw [4352..4607]   xcd table (16 groups x 16dw)
#define OFF_CNT   0
#define OFF_HBUF  20480
#define OFF_WT    (OFF_HBUF + 2*B_*U_*2)
#define OFF_WDEC  (OFF_WT + FOURU*KTOT*2)
#define OFF_DWT   (OFF_WDEC + FOURU*U_*2)
#define OFF_BDEC  (OFF_DWT + F_*U_*2)
#define OFF_XBF   (OFF_BDEC + FOURU*4)
#define WS_TOTAL  (OFF_XBF + (size_t)T_*B_*F_*2)

__device__ __forceinline__ short f2bf(float f) {
  union { float f; unsigned u; } a; a.f = f;
  unsigned u = a.u;
  unsigned r = u + 0x7FFFu + ((u >> 16) & 1u);  // RNE
  return (short)(r >> 16);
}
__device__ __forceinline__ float sigm(float x){ return 1.0f/(1.0f+__expf(-x)); }
__device__ __forceinline__ float tanh_(float x){ return 1.0f - 2.0f/(1.0f+__expf(2.0f*x)); }

template<int CTRL>
__device__ __forceinline__ float dppb(float x) {
  union { float f; int i; } a, b; a.f = x;
  b.i = __builtin_amdgcn_mov_dpp(a.i, CTRL, 0xF, 0xF, true);
  return b.f;
}
__device__ __forceinline__ float sel4(float x0, float x1, float x2, float x3, int qq) {
  float lo = (qq & 1) ? x1 : x0;
  float hi = (qq & 1) ? x3 : x2;
  return (qq & 2) ? hi : lo;
}

// ---------------- prep kernels ----------------
__global__ void prep_wt(const float* __restrict__ Wx, const float* __restrict__ Wh,
                        short* __restrict__ Wt) {
  int idx = blockIdx.x*256 + threadIdx.x;
  if (idx >= FOURU*KTOT) return;
  int c = idx / KTOT, k = idx % KTOT;
  float v = (k < F_) ? Wx[(size_t)k*FOURU + c] : Wh[(size_t)(k-F_)*FOURU + c];
  Wt[idx] = f2bf(v);
}
__global__ void prep_wdec(const float* __restrict__ Wh, const float* __restrict__ Wx,
                          const float* __restrict__ Dw, short* __restrict__ Wdec) {
  int idx = blockIdx.x*256 + threadIdx.x;
  if (idx >= FOURU*U_) return;
  int c = idx / U_, u = idx % U_;
  float a = Wh[(size_t)u*FOURU + c];
  for (int f=0; f<F_; ++f) a += Dw[u*F_ + f] * Wx[(size_t)f*FOURU + c];
  Wdec[idx] = f2bf(a);
}
__global__ void prep_bdec(const float* __restrict__ bv, const float* __restrict__ db,
                          const float* __restrict__ Wx, float* __restrict__ bdec) {
  int c = blockIdx.x*256 + threadIdx.x;
  if (c >= FOURU) return;
  float a = bv[c];
  for (int f=0; f<F_; ++f) a += db[f]*Wx[(size_t)f*FOURU + c];
  bdec[c] = a;
}
__global__ void prep_dwt(const float* __restrict__ Dw, short* __restrict__ Dwt) {
  int idx = blockIdx.x*256 + threadIdx.x;
  if (idx >= F_*U_) return;
  int f = idx / U_, u = idx % U_;
  Dwt[idx] = f2bf(Dw[u*F_ + f]);
}
__global__ void prep_x(const float* __restrict__ in, short* __restrict__ xbf) {
  int idx = blockIdx.x*256 + threadIdx.x;
  if (idx >= T_*B_*F_) return;
  int f = idx % F_, b = (idx / F_) % B_, t = idx / (F_*B_);
  xbf[idx] = f2bf(in[((size_t)b*T_ + t)*F_ + f]);
}

// ---------------- main persistent kernel ----------------
// 1024 threads = 16 waves, 1 block/CU -> 4 waves/SIMD.
// LDS weights: 128 cols (col = unit_local*4 + gate) x 576 K, XOR-swizzled 16B
// granules (granule g at g^(col&7)) -> conflict-free ds_read_b128 (validated r5).
// Sync: round-4 bulk barrier (ballot over 16 flags) -> compiler pipelines all
// 16 h-chunk loads per step (the r5 per-chunk gating serialized them).
__global__ __launch_bounds__(1024, 4) void lstm_main(
    const short* __restrict__ xbf, const short* __restrict__ Wt,
    const short* __restrict__ Wdec, const short* __restrict__ Dwt,
    const float* __restrict__ bvec, const float* __restrict__ bdec,
    const float* __restrict__ dbv, short* hbuf, unsigned* cnt,
    float* __restrict__ out)
{
  __shared__ short wlds[128*KTOT];   // 147,456 B
  __shared__ int sSame;
  const int tid = threadIdx.x;
  const int bidx = blockIdx.x;
  const int gb = (bidx & 7)*2 + (bidx >> 7);   // batch group 0..15
  const int gu = (bidx >> 3) & 15;             // unit group 0..15

  unsigned* flags  = cnt + gb*256;             // 16 producer flags, 64B spaced
  unsigned* myFlag = flags + gu*16;
  unsigned* regCnt = cnt + 4096 + gb*16;
  unsigned* xcdTab = cnt + 4352 + gb*16;

  // ---- runtime XCD-uniformity check for this group ----
  {
    unsigned xcc;
    asm volatile("s_getreg_b32 %0, hwreg(HW_REG_XCC_ID)" : "=s"(xcc));
    if (tid == 0) {
      __hip_atomic_store(&xcdTab[gu], xcc + 1u, __ATOMIC_RELAXED, __HIP_MEMORY_SCOPE_AGENT);
      __hip_atomic_fetch_add(regCnt, 1u, __ATOMIC_RELEASE, __HIP_MEMORY_SCOPE_AGENT);
      while (__hip_atomic_fetch_add(regCnt, 0u, __ATOMIC_RELAXED, __HIP_MEMORY_SCOPE_AGENT) < 16u)
        __builtin_amdgcn_s_sleep(1);
      __builtin_amdgcn_fence(__ATOMIC_ACQUIRE, "agent");
      unsigned x0 = __hip_atomic_load(&xcdTab[0], __ATOMIC_RELAXED, __HIP_MEMORY_SCOPE_AGENT);
      int same = 1;
      for (int i = 1; i < 16; ++i)
        same &= (__hip_atomic_load(&xcdTab[i], __ATOMIC_RELAXED, __HIP_MEMORY_SCOPE_AGENT) == x0);
      sSame = same;
    }
  }

  // ---- fill LDS weights (warm: full K=576), unit-major + swizzle ----
  {
    const int c = tid >> 3, q8 = tid & 7;
    const int gcol = (c & 3)*512 + gu*32 + (c >> 2);   // gate-major global col
    const int cx = c & 7;
    #pragma unroll
    for (int j = 0; j < 9; ++j) {
      const int g = q8*9 + j;                          // granule 0..71
      *(bf16x8*)(wlds + (size_t)c*KTOT + (size_t)(g ^ cx)*8) =
        *(const bf16x8*)(Wt + (size_t)gcol*KTOT + (size_t)g*8);
    }
  }
  __syncthreads();
  const bool fastSync = (sSame != 0);

  const int w  = tid >> 6, lane = tid & 63;
  const int wm = w >> 2, cq = w & 3;          // 4 row-groups x 4 col-quarters
  const int l15 = lane & 15, kh = lane >> 4;
  const int v = l15 >> 2, q = l15 & 3;        // unit-in-4 / gate
  const int R0 = gb*128, U0 = gu*32;
  const int cswz = l15 & 7;

  float bia[2], biaD[2];
  #pragma unroll
  for (int f = 0; f < 2; ++f) {
    const int uc = U0 + cq*8 + f*4 + v;
    bia[f]  = bvec[q*512 + uc];
    biaD[f] = bdec[q*512 + uc];
  }

  float cst[2][2] = {{0.f,0.f},{0.f,0.f}};    // c-state, row kh*4+q only
  const int rowA = R0 + wm*32 + l15;

  f32x4 acc[2][2];
  #pragma unroll
  for (int a = 0; a < 2; ++a)
    #pragma unroll
    for (int f = 0; f < 2; ++f) acc[a][f] = (f32x4){0.f,0.f,0.f,0.f};

  // x-part helper (K 0..63, granules 0..7)
  auto do_x = [&](int tt) {
    const short* xp = xbf + ((size_t)tt*B_ + rowA)*F_ + kh*8;
    bf16x8 X0a = *(const bf16x8*)(xp);
    bf16x8 X1a = *(const bf16x8*)(xp + 16*F_);
    bf16x8 X0b = *(const bf16x8*)(xp + 32);
    bf16x8 X1b = *(const bf16x8*)(xp + 16*F_ + 32);
    #pragma unroll
    for (int kx = 0; kx < 2; ++kx) {
      const int gsw = (kx*4 + kh) ^ cswz;
      bf16x8 B0 = *(const bf16x8*)(wlds + (size_t)(cq*32 + l15)*KTOT + (size_t)gsw*8);
      bf16x8 B1 = *(const bf16x8*)(wlds + (size_t)(cq*32 + 16 + l15)*KTOT + (size_t)gsw*8);
      bf16x8 Xa = kx ? X0b : X0a;
      bf16x8 Xb = kx ? X1b : X1a;
      acc[0][0] = __builtin_amdgcn_mfma_f32_16x16x32_bf16(Xa, B0, acc[0][0], 0,0,0);
      acc[0][1] = __builtin_amdgcn_mfma_f32_16x16x32_bf16(Xa, B1, acc[0][1], 0,0,0);
      acc[1][0] = __builtin_amdgcn_mfma_f32_16x16x32_bf16(Xb, B0, acc[1][0], 0,0,0);
      acc[1][1] = __builtin_amdgcn_mfma_f32_16x16x32_bf16(Xb, B1, acc[1][1], 0,0,0);
    }
  };
  do_x(0);   // h(0)=0, so step 0 is x-part + zero h-contribution

  for (int t = 0; t < 160; ++t) {
    // ---- wait: all 16 group flags >= t ----
    if (t > 0) {
      if (fastSync) {
        if (tid < 64) {
          unsigned* fl = flags + (tid & 15)*16;
          for (;;) {
            unsigned vv = __hip_atomic_load(fl, __ATOMIC_RELAXED, __HIP_MEMORY_SCOPE_AGENT);
            if (__ballot(vv >= (unsigned)t) == ~0ull) break;
            __builtin_amdgcn_s_sleep(1);
          }
          asm volatile("buffer_inv sc0" ::: "memory");     // L1 invalidate
          asm volatile("s_waitcnt vmcnt(0)" ::: "memory");
        }
      } else {
        if (tid < 64) {
          unsigned* fl = flags + (tid & 15)*16;
          for (;;) {
            unsigned vv = __hip_atomic_fetch_add(fl, 0u, __ATOMIC_RELAXED, __HIP_MEMORY_SCOPE_AGENT);
            if (__ballot(vv >= (unsigned)t) == ~0ull) break;
            __builtin_amdgcn_s_sleep(1);
          }
        }
        if (tid == 0)
          __builtin_amdgcn_fence(__ATOMIC_ACQUIRE, "agent");
      }
      __syncthreads();
    }

    const short* hcur = hbuf + (size_t)(t & 1)*B_*U_;
    short* hnxt = hbuf + (size_t)((t+1) & 1)*B_*U_;

    // ---- pred s = t-128 (reads h(t) just finalized; distributed gu<8, w<4) ----
    if (t >= 128 && gu < 8 && w < 4) {
      const int s = t - 128;
      const int pr0 = R0 + gu*16 + l15;
      f32x4 pa = {0.f,0.f,0.f,0.f};
      #pragma unroll
      for (int ks2 = 0; ks2 < 16; ++ks2) {
        bf16x8 a2 = *(const bf16x8*)(hcur + (size_t)pr0*U_ + ks2*32 + kh*8);
        bf16x8 b2 = *(const bf16x8*)(Dwt + (size_t)(w*16 + l15)*U_ + ks2*32 + kh*8);
        pa = __builtin_amdgcn_mfma_f32_16x16x32_bf16(a2, b2, pa, 0,0,0);
      }
      const int col = w*16 + l15;
      const float dbc = dbv[col];
      #pragma unroll
      for (int r = 0; r < 4; ++r) {
        const int orow = R0 + gu*16 + kh*4 + r;
        out[((size_t)orow*OUTS + s)*F_ + col] = pa[r] + dbc;
      }
    }
    if (t == 159) break;
    if (t == 128) {   // swap k-region 64..575 (granules 8..71) to folded Wdec
      const int c = tid >> 3, q8 = tid & 7;
      const int gcol = (c & 3)*512 + gu*32 + (c >> 2);
      const int cx = c & 7;
      #pragma unroll
      for (int j = 0; j < 8; ++j) {
        const int g = 8 + q8*8 + j;
        *(bf16x8*)(wlds + (size_t)c*KTOT + (size_t)(g ^ cx)*8) =
          *(const bf16x8*)(Wdec + (size_t)gcol*U_ + (size_t)(g-8)*8);
      }
      __syncthreads();
    }

    // ---- h-part: K 64..575, 16 chunks bulk (compiler pipelines the loads) ----
    {
      const short* hp = hcur + (size_t)rowA*U_ + kh*8;
      #pragma unroll
      for (int ks = 0; ks < 16; ++ks) {
        bf16x8 A0 = *(const bf16x8*)(hp + ks*32);
        bf16x8 A1 = *(const bf16x8*)(hp + 16*U_ + ks*32);
        const int gsw = (8 + ks*4 + kh) ^ cswz;
        bf16x8 B0 = *(const bf16x8*)(wlds + (size_t)(cq*32 + l15)*KTOT + (size_t)gsw*8);
        bf16x8 B1 = *(const bf16x8*)(wlds + (size_t)(cq*32 + 16 + l15)*KTOT + (size_t)gsw*8);
        acc[0][0] = __builtin_amdgcn_mfma_f32_16x16x32_bf16(A0, B0, acc[0][0], 0,0,0);
        acc[0][1] = __builtin_amdgcn_mfma_f32_16x16x32_bf16(A0, B1, acc[0][1], 0,0,0);
        acc[1][0] = __builtin_amdgcn_mfma_f32_16x16x32_bf16(A1, B0, acc[1][0], 0,0,0);
        acc[1][1] = __builtin_amdgcn_mfma_f32_16x16x32_bf16(A1, B1, acc[1][1], 0,0,0);
      }
    }

    // ---- elementwise: quad-DPP gate gather, each lane owns row kh*4+q ----
    {
      const bool warm = (t < T_);
      #pragma unroll
      for (int a = 0; a < 2; ++a)
      #pragma unroll
      for (int f = 0; f < 2; ++f) {
        const float bb = warm ? bia[f] : biaD[f];
        float z0 = acc[a][f][0] + bb, z1 = acc[a][f][1] + bb;
        float z2 = acc[a][f][2] + bb, z3 = acc[a][f][3] + bb;
        float zi = sel4(dppb<0x00>(z0), dppb<0x00>(z1), dppb<0x00>(z2), dppb<0x00>(z3), q);
        float zf = sel4(dppb<0x55>(z0), dppb<0x55>(z1), dppb<0x55>(z2), dppb<0x55>(z3), q);
        float zg = sel4(dppb<0xAA>(z0), dppb<0xAA>(z1), dppb<0xAA>(z2), dppb<0xAA>(z3), q);
        float zo = sel4(dppb<0xFF>(z0), dppb<0xFF>(z1), dppb<0xFF>(z2), dppb<0xFF>(z3), q);
        float ig = sigm(zi), fg = sigm(zf), gg = tanh_(zg), og = sigm(zo);
        float c2 = fmaf(fg, cst[a][f], ig*gg);
        cst[a][f] = c2;
        float h2 = og*tanh_(c2);
        hnxt[(size_t)(R0 + wm*32 + a*16 + kh*4 + q)*U_ + U0 + cq*8 + f*4 + v] = f2bf(h2);
      }
    }

    // ---- release: all waves drained (syncthreads emits vmcnt(0)), set flag ----
    __syncthreads();
    if (tid == 0) {
      if (fastSync)
        __hip_atomic_store(myFlag, (unsigned)(t+1), __ATOMIC_RELAXED, __HIP_MEMORY_SCOPE_AGENT);
      else
        __hip_atomic_fetch_add(myFlag, 1u, __ATOMIC_RELEASE, __HIP_MEMORY_SCOPE_AGENT);
    }

    // ---- next step's x-part (shadows inter-block flag latency) ----
    #pragma unroll
    for (int a = 0; a < 2; ++a)
      #pragma unroll
      for (int f = 0; f < 2; ++f) acc[a][f] = (f32x4){0.f,0.f,0.f,0.f};
    if (t + 1 < T_) do_x(t+1);
  }
}

extern "C" void kernel_launch(void* const* d_in, const int* in_sizes, int n_in,
                              void* d_out, int out_size, void* d_ws, size_t ws_size,
                              hipStream_t stream) {
  const float* inputs = (const float*)d_in[0];
  const float* Wx = (const float*)d_in[1];
  const float* Wh = (const float*)d_in[2];
  const float* bv = (const float*)d_in[3];
  const float* Dw = (const float*)d_in[4];
  const float* db = (const float*)d_in[5];
  float* out = (float*)d_out;
  char* ws = (char*)d_ws;
  if (ws_size < WS_TOTAL) return;   // fail loudly (output stays poisoned)

  unsigned* cnt = (unsigned*)(ws + OFF_CNT);
  short* hbuf = (short*)(ws + OFF_HBUF);
  short* Wt   = (short*)(ws + OFF_WT);
  short* Wdec = (short*)(ws + OFF_WDEC);
  short* Dwt  = (short*)(ws + OFF_DWT);
  float* bdec = (float*)(ws + OFF_BDEC);
  short* xbf  = (short*)(ws + OFF_XBF);

  // zero sync area + h0 buffer (every launch -> deterministic)
  hipMemsetAsync(d_ws, 0, OFF_HBUF + (size_t)B_*U_*2, stream);
  prep_wt  <<<(FOURU*KTOT+255)/256, 256, 0, stream>>>(Wx, Wh, Wt);
  prep_wdec<<<(FOURU*U_ +255)/256, 256, 0, stream>>>(Wh, Wx, Dw, Wdec);
  prep_bdec<<<(FOURU     +255)/256, 256, 0, stream>>>(bv, db, Wx, bdec);
  prep_dwt <<<(F_*U_     +255)/256, 256, 0, stream>>>(Dw, Dwt);
  prep_x   <<<(T_*B_*F_  +255)/256, 256, 0, stream>>>(inputs, xbf);
  lstm_main<<<256, 1024, 0, stream>>>(xbf, Wt, Wdec, Dwt, bv, bdec, db, hbuf, cnt, out);
}

// Round 7
// 1996.216 us; speedup vs baseline: 1.5661x; 1.5509x over previous
//
#include <hip/hip_runtime.h>
#include <hip/hip_bf16.h>

#define B_ 2048
#define T_ 128
#define F_ 64
#define U_ 512
#define FOURU 2048
#define OUTS 32
#define ROWS 128      // batch rows per group
#define COLSB 128     // z cols per block (4 gates x 32 units)
#define KTOT 576      // 64 (x) + 512 (h)
#define LDSTR 584     // padded LDS col stride (elements)

typedef __attribute__((ext_vector_type(8))) short bf16x8;
typedef __attribute__((ext_vector_type(4))) float f32x4;

// workspace layout (bytes). First 20480 B zeroed every launch:
//   dw [0..4095]      flags: group gb, block gu at dw gb*256+gu*16 (64B spaced)
//   dw [4096..4351]   regist counters (16 groups x 16dw)
//   dw [4352..4607]   xcd table (16 groups x 16dw)
#define OFF_CNT   0
#define OFF_HBUF  20480
#define OFF_WT    (OFF_HBUF + 3*B_*U_*2)          // TRIPLE-buffered h
#define OFF_WDEC  (OFF_WT + FOURU*KTOT*2)
#define OFF_DWT   (OFF_WDEC + FOURU*U_*2)
#define OFF_BDEC  (OFF_DWT + F_*U_*2)
#define OFF_XBF   (OFF_BDEC + FOURU*4)
#define WS_TOTAL  (OFF_XBF + (size_t)T_*B_*F_*2)

__device__ __forceinline__ short f2bf(float f) {
  union { float f; unsigned u; } a; a.f = f;
  unsigned u = a.u;
  unsigned r = u + 0x7FFFu + ((u >> 16) & 1u);  // RNE
  return (short)(r >> 16);
}
__device__ __forceinline__ float sigm(float x){ return 1.0f/(1.0f+__expf(-x)); }
__device__ __forceinline__ float tanh_(float x){ return 1.0f - 2.0f/(1.0f+__expf(2.0f*x)); }

// ---------------- prep kernels ----------------
__global__ void prep_wt(const float* __restrict__ Wx, const float* __restrict__ Wh,
                        short* __restrict__ Wt) {
  int idx = blockIdx.x*256 + threadIdx.x;
  if (idx >= FOURU*KTOT) return;
  int c = idx / KTOT, k = idx % KTOT;
  float v = (k < F_) ? Wx[(size_t)k*FOURU + c] : Wh[(size_t)(k-F_)*FOURU + c];
  Wt[idx] = f2bf(v);
}
__global__ void prep_wdec(const float* __restrict__ Wh, const float* __restrict__ Wx,
                          const float* __restrict__ Dw, short* __restrict__ Wdec) {
  int idx = blockIdx.x*256 + threadIdx.x;
  if (idx >= FOURU*U_) return;
  int c = idx / U_, u = idx % U_;
  float a = Wh[(size_t)u*FOURU + c];
  for (int f=0; f<F_; ++f) a += Dw[u*F_ + f] * Wx[(size_t)f*FOURU + c];
  Wdec[idx] = f2bf(a);
}
__global__ void prep_bdec(const float* __restrict__ bv, const float* __restrict__ db,
                          const float* __restrict__ Wx, float* __restrict__ bdec) {
  int c = blockIdx.x*256 + threadIdx.x;
  if (c >= FOURU) return;
  float a = bv[c];
  for (int f=0; f<F_; ++f) a += db[f]*Wx[(size_t)f*FOURU + c];
  bdec[c] = a;
}
__global__ void prep_dwt(const float* __restrict__ Dw, short* __restrict__ Dwt) {
  int idx = blockIdx.x*256 + threadIdx.x;
  if (idx >= F_*U_) return;
  int f = idx / U_, u = idx % U_;
  Dwt[idx] = f2bf(Dw[u*F_ + f]);
}
__global__ void prep_x(const float* __restrict__ in, short* __restrict__ xbf) {
  int idx = blockIdx.x*256 + threadIdx.x;
  if (idx >= T_*B_*F_) return;
  int f = idx % F_, b = (idx / F_) % B_, t = idx / (F_*B_);
  xbf[idx] = f2bf(in[((size_t)b*T_ + t)*F_ + f]);
}

// ---------------- main persistent kernel ----------------
// 1024 threads = 16 waves; 1 block/CU (LDS-bound) -> 4 waves/SIMD.
// R4 base (gate-major LDS, 16x64 wave tiles) + reg B-cache (ks 0..3) +
// triple-buffered h + pred in the post-flag shadow region.
__global__ __launch_bounds__(1024, 4) void lstm_main(
    const short* __restrict__ xbf, const short* __restrict__ Wt,
    const short* __restrict__ Wdec, const short* __restrict__ Dwt,
    const float* __restrict__ bvec, const float* __restrict__ bdec,
    const float* __restrict__ dbv, short* hbuf, unsigned* cnt,
    float* __restrict__ out)
{
  __shared__ short wlds[COLSB*LDSTR];   // 149,504 B
  __shared__ int sSame;
  const int tid = threadIdx.x;
  const int bidx = blockIdx.x;
  // a group's 16 blocks share bidx%8 -> same XCD under round-robin dispatch
  // (perf heuristic; verified at runtime below, fallback is cross-XCD safe)
  const int gb = (bidx & 7)*2 + (bidx >> 7);   // batch group 0..15
  const int gu = (bidx >> 3) & 15;             // unit group 0..15

  unsigned* flags  = cnt + gb*256;             // 16 flags, 64B spaced
  unsigned* myFlag = flags + gu*16;
  unsigned* regCnt = cnt + 4096 + gb*16;
  unsigned* xcdTab = cnt + 4352 + gb*16;

  // ---- runtime XCD-uniformity check for this group ----
  {
    unsigned xcc;
    asm volatile("s_getreg_b32 %0, hwreg(HW_REG_XCC_ID)" : "=s"(xcc));
    if (tid == 0) {
      __hip_atomic_store(&xcdTab[gu], xcc + 1u, __ATOMIC_RELAXED, __HIP_MEMORY_SCOPE_AGENT);
      __hip_atomic_fetch_add(regCnt, 1u, __ATOMIC_RELEASE, __HIP_MEMORY_SCOPE_AGENT);
      while (__hip_atomic_fetch_add(regCnt, 0u, __ATOMIC_RELAXED, __HIP_MEMORY_SCOPE_AGENT) < 16u)
        __builtin_amdgcn_s_sleep(1);
      __builtin_amdgcn_fence(__ATOMIC_ACQUIRE, "agent");
      unsigned x0 = __hip_atomic_load(&xcdTab[0], __ATOMIC_RELAXED, __HIP_MEMORY_SCOPE_AGENT);
      int same = 1;
      for (int i = 1; i < 16; ++i)
        same &= (__hip_atomic_load(&xcdTab[i], __ATOMIC_RELAXED, __HIP_MEMORY_SCOPE_AGENT) == x0);
      sSame = same;
    }
  }

  // ---- load warm-up weight slice to LDS (col=tid>>3, 72 B each) ----
  {
    const int c = tid >> 3, q = tid & 7;
    const int gate = (c >> 4) & 3;
    const int u = gu*32 + ((c >> 6) << 4) + (c & 15);
    const int gcol = gate*512 + u;
    const short* src = Wt + (size_t)gcol*KTOT + q*72;
    short* dst = wlds + c*LDSTR + q*72;
    #pragma unroll
    for (int j=0;j<9;j++)
      *(bf16x8*)(dst + j*8) = *(const bf16x8*)(src + j*8);
  }
  __syncthreads();
  const bool fastSync = (sSame != 0);

  const int w = tid >> 6, lane = tid & 63;
  const int wm = w >> 1, wn = w & 1;           // 8 row-groups x 2 col-halves
  const int l15 = lane & 15, kh = lane >> 4;

  const int ucol = gu*32 + wn*16 + l15;        // unit column this lane updates
  float bia[4], biaD[4];
  #pragma unroll
  for (int g=0; g<4; ++g){ bia[g] = bvec[g*512 + ucol]; biaD[g] = bdec[g*512 + ucol]; }

  float cst[4] = {};                           // c state (fp32, persistent)
  const int rowA = gb*ROWS + wm*16 + l15;      // A-frag row for this lane

  // ---- register B-cache: ks 0..3 of the h-region (step-invariant weights) ----
  bf16x8 Bc[4][4];                             // 64 VGPRs
  auto loadBc = [&]() {
    #pragma unroll
    for (int ks=0; ks<4; ++ks)
      #pragma unroll
      for (int g=0; g<4; ++g)
        Bc[ks][g] = *(const bf16x8*)(wlds + (size_t)(wn*64 + 16*g + l15)*LDSTR + 64 + ks*32 + kh*8);
  };
  loadBc();

  f32x4 acc[4];
  // x-part helper (K 0..63): assigns acc fresh
  auto do_x = [&](int tt) {
    const short* xp = xbf + ((size_t)tt*B_ + rowA)*F_ + kh*8;
    bf16x8 a0 = *(const bf16x8*)(xp);
    bf16x8 a1 = *(const bf16x8*)(xp + 32);
    #pragma unroll
    for (int g=0; g<4; ++g) {
      bf16x8 b0 = *(const bf16x8*)(wlds + (size_t)(wn*64 + 16*g + l15)*LDSTR + kh*8);
      bf16x8 b1 = *(const bf16x8*)(wlds + (size_t)(wn*64 + 16*g + l15)*LDSTR + 32 + kh*8);
      f32x4 z = {0.f,0.f,0.f,0.f};
      z = __builtin_amdgcn_mfma_f32_16x16x32_bf16(a0, b0, z, 0,0,0);
      acc[g] = __builtin_amdgcn_mfma_f32_16x16x32_bf16(a1, b1, z, 0,0,0);
    }
  };
  do_x(0);   // h(0)=0 (buf0 zeroed), so step 0 = x-part + zero h-contribution

  for (int t = 0; t < 160; ++t) {
    // ---- wait: all 16 group flags >= t ----
    if (t > 0) {
      if (fastSync) {
        if (tid < 64) {
          unsigned* fl = flags + (tid & 15)*16;
          for (;;) {
            unsigned vv = __hip_atomic_load(fl, __ATOMIC_RELAXED, __HIP_MEMORY_SCOPE_AGENT);
            if (__ballot(vv >= (unsigned)t) == ~0ull) break;
            __builtin_amdgcn_s_sleep(1);
          }
          asm volatile("buffer_inv sc0" ::: "memory");     // L1 invalidate
          asm volatile("s_waitcnt vmcnt(0)" ::: "memory");
        }
      } else {
        if (tid < 64) {
          unsigned* fl = flags + (tid & 15)*16;
          for (;;) {
            unsigned vv = __hip_atomic_fetch_add(fl, 0u, __ATOMIC_RELAXED, __HIP_MEMORY_SCOPE_AGENT);
            if (__ballot(vv >= (unsigned)t) == ~0ull) break;
            __builtin_amdgcn_s_sleep(1);
          }
        }
        if (tid == 0)
          __builtin_amdgcn_fence(__ATOMIC_ACQUIRE, "agent");
      }
      __syncthreads();
    }

    const int cur = t % 3;
    const short* hcur = hbuf + (size_t)cur*B_*U_;

    if (t < 159) {
      if (t == 128) {   // swap k-region 64..575 to folded decode weights
        const int c = tid >> 3, q = tid & 7;
        const int gate = (c >> 4) & 3;
        const int u = gu*32 + ((c >> 6) << 4) + (c & 15);
        const int gcol = gate*512 + u;
        const short* src = Wdec + (size_t)gcol*U_ + q*64;
        short* dst = wlds + c*LDSTR + 64 + q*64;
        #pragma unroll
        for (int j=0;j<8;j++)
          *(bf16x8*)(dst + j*8) = *(const bf16x8*)(src + j*8);
        __syncthreads();
        loadBc();       // refresh register B-cache from the new weights
      }

      short* hnxt = hbuf + (size_t)((t+1) % 3)*B_*U_;

      // ---- h-part: K 64..575, 16 chunks; ks 0..3 hit the register cache ----
      {
        const short* hp = hcur + (size_t)rowA*U_ + kh*8;
        #pragma unroll
        for (int ks=0; ks<16; ++ks) {
          bf16x8 a = *(const bf16x8*)(hp + ks*32);
          #pragma unroll
          for (int g=0; g<4; ++g) {
            bf16x8 b = (ks < 4) ? Bc[ks][g]
              : *(const bf16x8*)(wlds + (size_t)(wn*64 + 16*g + l15)*LDSTR + 64 + ks*32 + kh*8);
            acc[g] = __builtin_amdgcn_mfma_f32_16x16x32_bf16(a, b, acc[g], 0,0,0);
          }
        }
      }

      // ---- gates + state update + h2 store (C/D: col=l15, row=kh*4+r) ----
      {
        const bool warm = (t < T_);
        #pragma unroll
        for (int r=0; r<4; ++r) {
          float zi = acc[0][r] + (warm ? bia[0] : biaD[0]);
          float zf = acc[1][r] + (warm ? bia[1] : biaD[1]);
          float zg = acc[2][r] + (warm ? bia[2] : biaD[2]);
          float zo = acc[3][r] + (warm ? bia[3] : biaD[3]);
          float ig = sigm(zi), fg = sigm(zf), gg = tanh_(zg), og = sigm(zo);
          float c2 = fmaf(fg, cst[r], ig*gg);
          cst[r] = c2;
          float h2 = og*tanh_(c2);
          const int row = gb*ROWS + wm*16 + kh*4 + r;
          hnxt[(size_t)row*U_ + ucol] = f2bf(h2);
        }
      }

      // ---- release: drain stores (syncthreads emits vmcnt(0)), set flag ----
      __syncthreads();
      if (tid == 0) {
        if (fastSync)
          __hip_atomic_store(myFlag, (unsigned)(t+1), __ATOMIC_RELAXED, __HIP_MEMORY_SCOPE_AGENT);
        else
          __hip_atomic_fetch_add(myFlag, 1u, __ATOMIC_RELEASE, __HIP_MEMORY_SCOPE_AGENT);
      }
    }

    // ======== shadow region (off the group critical path) ========
    // pred s = t-128 reads h(t) = buf[t%3]; triple-buffering guarantees no
    // writer touches buf[t%3] until our flag(t+2), which is after this code.
    if (t >= 128 && gu < 8 && w < 4) {
      const int s = t - 128;
      const int pr0 = gb*ROWS + gu*16 + l15;
      f32x4 pa = {0.f,0.f,0.f,0.f};
      #pragma unroll
      for (int ks=0; ks<16; ++ks) {
        bf16x8 a = *(const bf16x8*)(hcur + (size_t)pr0*U_ + ks*32 + kh*8);
        bf16x8 b = *(const bf16x8*)(Dwt + (size_t)(w*16 + l15)*U_ + ks*32 + kh*8);
        pa = __builtin_amdgcn_mfma_f32_16x16x32_bf16(a, b, pa, 0,0,0);
      }
      const int col = w*16 + l15;
      const float dbc = dbv[col];
      #pragma unroll
      for (int r=0; r<4; ++r) {
        const int orow = gb*ROWS + gu*16 + kh*4 + r;
        out[((size_t)orow*OUTS + s)*F_ + col] = pa[r] + dbc;
      }
    }

    // ---- next step's x-part (shadows inter-block flag latency) ----
    #pragma unroll
    for (int g=0; g<4; ++g) acc[g] = (f32x4){0.f,0.f,0.f,0.f};
    if (t + 1 < T_) do_x(t+1);
  }
}

extern "C" void kernel_launch(void* const* d_in, const int* in_sizes, int n_in,
                              void* d_out, int out_size, void* d_ws, size_t ws_size,
                              hipStream_t stream) {
  const float* inputs = (const float*)d_in[0];
  const float* Wx = (const float*)d_in[1];
  const float* Wh = (const float*)d_in[2];
  const float* bv = (const float*)d_in[3];
  const float* Dw = (const float*)d_in[4];
  const float* db = (const float*)d_in[5];
  float* out = (float*)d_out;
  char* ws = (char*)d_ws;
  if (ws_size < WS_TOTAL) return;   // fail loudly (output stays poisoned)

  unsigned* cnt = (unsigned*)(ws + OFF_CNT);
  short* hbuf = (short*)(ws + OFF_HBUF);
  short* Wt   = (short*)(ws + OFF_WT);
  short* Wdec = (short*)(ws + OFF_WDEC);
  short* Dwt  = (short*)(ws + OFF_DWT);
  float* bdec = (float*)(ws + OFF_BDEC);
  short* xbf  = (short*)(ws + OFF_XBF);

  // zero sync area + h buffer 0 (every launch -> deterministic)
  hipMemsetAsync(d_ws, 0, OFF_HBUF + (size_t)B_*U_*2, stream);
  prep_wt  <<<(FOURU*KTOT+255)/256, 256, 0, stream>>>(Wx, Wh, Wt);
  prep_wdec<<<(FOURU*U_ +255)/256, 256, 0, stream>>>(Wh, Wx, Dw, Wdec);
  prep_bdec<<<(FOURU     +255)/256, 256, 0, stream>>>(bv, db, Wx, bdec);
  prep_dwt <<<(F_*U_     +255)/256, 256, 0, stream>>>(Dw, Dwt);
  prep_x   <<<(T_*B_*F_  +255)/256, 256, 0, stream>>>(inputs, xbf);
  lstm_main<<<256, 1024, 0, stream>>>(xbf, Wt, Wdec, Dwt, bv, bdec, db, hbuf, cnt, out);
}